// Round 19
// baseline (1690.079 us; speedup 1.0000x reference)
//
#include <hip/hip_runtime.h>
#include <hip/hip_bf16.h>
#include <math.h>

#define HH 32
#define LL 3
#define DS 512
#define DID 128
#define DSTEER 1664
#define DHID 2048
#define HDQ 1024
#define BHROWS 32768

typedef __attribute__((ext_vector_type(8))) short short8;
typedef __attribute__((ext_vector_type(4))) float f32x4;

typedef const __attribute__((address_space(1))) unsigned int* gptr_t;
typedef __attribute__((address_space(3))) unsigned int* lptr_t;

#define BAR() __builtin_amdgcn_s_barrier()
#define SB()  __builtin_amdgcn_sched_barrier(0)
#define VMCNT0() asm volatile("s_waitcnt vmcnt(0)")

__device__ __forceinline__ unsigned short f2bf(float f) {
  union { float f; unsigned int u; } x; x.f = f;
  unsigned int r = (x.u + 0x7FFFu + ((x.u >> 16) & 1u)) >> 16;
  return (unsigned short)r;
}
__device__ __forceinline__ unsigned int pk2(float a, float b) {
  return (unsigned int)f2bf(a) | ((unsigned int)f2bf(b) << 16);
}
// fast tanh-form gelu (validated r14/r15: absmax unchanged vs erff path)
__device__ __forceinline__ float gelu_fast(float v) {
  float u = 0.79788456080286536f * v * fmaf(0.044715f * v, v, 1.0f);
  u = fminf(fmaxf(u, -9.0f), 9.0f);
  float t = __builtin_amdgcn_exp2f(-2.8853900817779268f * u);
  float r = __builtin_amdgcn_rcpf(1.0f + t);
  float th = fmaf(-2.0f * t, r, 1.0f);
  return 0.5f * v * (1.0f + th);
}

// ---------- fp32 -> bf16 bulk convert ----------
__global__ void cvt_bf16_kernel(const float4* __restrict__ in, uint2* __restrict__ out, long n4) {
  long i = (long)blockIdx.x * blockDim.x + threadIdx.x;
  long stride = (long)gridDim.x * blockDim.x;
  for (; i < n4; i += stride) {
    float4 v = in[i];
    uint2 o; o.x = pk2(v.x, v.y); o.y = pk2(v.z, v.w);
    out[i] = o;
  }
}

// ---------- fused cvt + row-permute: fp32 rows (b*32+h) -> bf16 head-major (h*1024+b) ----------
__global__ void cvt_permute_kernel(const float4* __restrict__ in, uint4* __restrict__ out) {
  const int s = blockIdx.x;            // src row
  const int b = s >> 5, h = s & 31;
  const long d = (long)h * 1024 + b;   // dst row (head-major)
  const float4* src = in + (long)s * (DSTEER / 4);
  uint4* dst = out + d * (DSTEER / 8);
  int t = threadIdx.x;
  if (t < DSTEER / 8) {
    float4 a = src[2 * t], c = src[2 * t + 1];
    uint4 o;
    o.x = pk2(a.x, a.y); o.y = pk2(a.z, a.w);
    o.z = pk2(c.x, c.y); o.w = pk2(c.z, c.w);
    dst[t] = o;
  }
}

// ---------- batched transpose + convert: fp32 [R][C] -> bf16 [C][R] ----------
__global__ void transpose_cvt_kernel(const float* __restrict__ in, long long in_bstride,
                                     unsigned short* __restrict__ out, long long out_bstride,
                                     int R, int C) {
  __shared__ float t[64][33];
  const int r0 = blockIdx.y * 32;
  const int c0 = blockIdx.x * 64;
  const float* bin = in + (long long)blockIdx.z * in_bstride;
  unsigned short* bout = out + (long long)blockIdx.z * out_bstride;
  const int tid = threadIdx.x;
  const int col = tid & 63, rr = tid >> 6;
  #pragma unroll
  for (int j = 0; j < 8; j++) {
    int r = j * 4 + rr;
    t[col][r] = bin[(size_t)(r0 + r) * C + c0 + col];
  }
  __syncthreads();
  const int rq = (tid & 7) * 4;
  const int cc = tid >> 3;
  #pragma unroll
  for (int j = 0; j < 2; j++) {
    int c = j * 32 + cc;
    float v0 = t[c][rq], v1 = t[c][rq + 1], v2 = t[c][rq + 2], v3 = t[c][rq + 3];
    uint2 o; o.x = pk2(v0, v1); o.y = pk2(v2, v3);
    *(uint2*)&bout[(size_t)(c0 + c) * R + r0 + rq] = o;
  }
}

// ---------- RMS-norm + scale -> bf16 (HEAD-MAJOR rows) ----------
__global__ void rms_scale_kernel(const float* __restrict__ h,
                                 const float* __restrict__ norm_w,
                                 unsigned short* __restrict__ xn, int layer) {
  int gw = (int)((blockIdx.x * blockDim.x + threadIdx.x) >> 6);
  int lane = threadIdx.x & 63;
  if (gw >= BHROWS) return;
  int head = gw >> 10;
  const float4* hr = (const float4*)(h + (size_t)gw * DS);
  float4 v0 = hr[lane * 2], v1 = hr[lane * 2 + 1];
  float ss = v0.x*v0.x + v0.y*v0.y + v0.z*v0.z + v0.w*v0.w
           + v1.x*v1.x + v1.y*v1.y + v1.z*v1.z + v1.w*v1.w;
  #pragma unroll
  for (int off = 32; off > 0; off >>= 1) ss += __shfl_xor(ss, off, 64);
  float r = rsqrtf(ss * (1.0f / DS) + 1e-6f);
  const float4* nw = (const float4*)(norm_w + ((size_t)head * LL + layer) * DS);
  float4 w0 = nw[lane * 2], w1 = nw[lane * 2 + 1];
  uint4 o;
  o.x = pk2(v0.x * r * w0.x, v0.y * r * w0.y);
  o.y = pk2(v0.z * r * w0.z, v0.w * r * w0.w);
  o.z = pk2(v1.x * r * w1.x, v1.y * r * w1.y);
  o.w = pk2(v1.z * r * w1.z, v1.w * r * w1.w);
  *(uint4*)(xn + (size_t)gw * DS + (size_t)lane * 8) = o;
}

// ---------- 256x256 tile, BK=32, 8-wave, 64KB LDS, 2 blocks/CU bf16 GEMM ----------
// Same FETCH profile as the 256x256/BK64 core but half the LDS -> 2 resident
// blocks per CU: barrier/drain stalls of one block overlap the other's MFMA
// (m114 mechanism). One barrier + one vmcnt(0) per 32-K tile.
// B LDS-row <-> global-col permutation preserved from the r17 core; swizzle:
// slot (lane&3) holds k-quarter (lane&3)^((row>>1)&3); read phys =
// ((lane>>4)^((lane>>1)&3))*8 (r14-measured conflict-free pattern).
template<int EPI>
__global__ __launch_bounds__(512, 2)
void gemm256_kernel(const unsigned short* __restrict__ A, long long a_hstride, long long a_rstride,
                    const unsigned short* __restrict__ Bt, long long b_hstride,
                    const float* __restrict__ bias, int bias_hstride,
                    const float* __restrict__ resid, long long r_hstride, long long r_rstride,
                    void* __restrict__ Cv, long long c_hstride, long long c_rstride,
                    int gx, int tph, int K) {
  __shared__ unsigned short lds[2 * 2 * 256 * 32];  // 64 KiB
  const int tid = threadIdx.x;
  const int lane = tid & 63;
  const int wave = tid >> 6;
  const int wr = wave >> 2, wc = wave & 3;
  const int ntot = gridDim.x;
  int id = blockIdx.x;
  { int cpx = ntot >> 3; id = (id & 7) * cpx + (id >> 3); }  // bijective: ntot%8==0
  const int head = id / tph;
  const int rem = id % tph;
  const int tn = rem % gx, tm = rem / gx;

  // ---- staging addressing: 16 consecutive rows per wave per instr ----
  const int lloc = wave * 16 + (lane >> 2);          // local row 0..127
  const int ksw = ((lane & 3) ^ ((lane >> 3) & 3)) * 8;  // inverse-swizzled k offset
  // B col for LDS row lloc (r17-compatible permutation), call j adds +32
  const int wf = (lloc >> 3) & 7;
  const int g0 = (lloc >> 6) * 128 + (wf >> 2) * 64 + (wf & 3) * 8 + (lloc & 7);
  const unsigned short* pA0 = A + (size_t)head * a_hstride
                                + (size_t)(tm * 256 + lloc) * a_rstride + ksw;
  const unsigned short* pA1 = A + (size_t)head * a_hstride
                                + (size_t)(tm * 256 + 128 + lloc) * a_rstride + ksw;
  const unsigned short* pB0 = Bt + (size_t)head * b_hstride
                                + (size_t)(tn * 256 + g0) * K + ksw;
  const unsigned short* pB1 = Bt + (size_t)head * b_hstride
                                + (size_t)(tn * 256 + g0 + 32) * K + ksw;
  const int ldst0 = (wave * 16) * 32;
  const int ldst1 = (128 + wave * 16) * 32;

#define STAGE(buf, kb) do { \
    __builtin_amdgcn_global_load_lds((gptr_t)(pA0 + (kb)), (lptr_t)((buf) + ldst0), 16, 0, 0); \
    __builtin_amdgcn_global_load_lds((gptr_t)(pA1 + (kb)), (lptr_t)((buf) + ldst1), 16, 0, 0); \
    __builtin_amdgcn_global_load_lds((gptr_t)(pB0 + (kb)), (lptr_t)((buf) + 8192 + ldst0), 16, 0, 0); \
    __builtin_amdgcn_global_load_lds((gptr_t)(pB1 + (kb)), (lptr_t)((buf) + 8192 + ldst1), 16, 0, 0); \
  } while (0)

  // ---- fragment read addressing ----
  const int physk = ((lane >> 4) ^ ((lane >> 1) & 3)) * 8;
  const int aRow = wr * 128 + (lane & 15);
  const int bRow = wc * 32 + (lane & 15);

  f32x4 acc[8][4];
  #pragma unroll
  for (int i = 0; i < 8; ++i)
    #pragma unroll
    for (int j = 0; j < 4; ++j) acc[i][j] = (f32x4){0.f, 0.f, 0.f, 0.f};

  const int T = K >> 5;
  STAGE(lds, 0);
  VMCNT0(); SB();
  BAR();

  for (int t = 0; t < T; ++t) {
    unsigned short* cur = lds + (t & 1) * 16384;
    unsigned short* nxt = lds + ((t + 1) & 1) * 16384;
    if (t + 1 < T) STAGE(nxt, (size_t)(t + 1) * 32);
    short8 bfr[4], a[8];
    #pragma unroll
    for (int j = 0; j < 4; ++j)
      bfr[j] = *(const short8*)&cur[8192 + ((j >> 1) * 128 + bRow + (j & 1) * 16) * 32 + physk];
    #pragma unroll
    for (int i = 0; i < 8; ++i)
      a[i] = *(const short8*)&cur[(aRow + i * 16) * 32 + physk];
    __builtin_amdgcn_s_setprio(1);
    #pragma unroll
    for (int i = 0; i < 8; ++i)
      #pragma unroll
      for (int j = 0; j < 4; ++j)
        acc[i][j] = __builtin_amdgcn_mfma_f32_16x16x32_bf16(a[i], bfr[j], acc[i][j], 0, 0, 0);
    __builtin_amdgcn_s_setprio(0);
    VMCNT0(); SB();
    BAR();
  }
#undef STAGE

  // ---- epilogue (same C/D map as r17) ----
  const float* bptr = bias + (size_t)head * bias_hstride;
  #pragma unroll
  for (int i = 0; i < 8; ++i) {
    #pragma unroll
    for (int j = 0; j < 4; ++j) {
      #pragma unroll
      for (int r = 0; r < 4; ++r) {
        int rowt = wr * 128 + i * 16 + (lane >> 4) * 4 + r;
        int colt = wc * 64 + j * 16 + (lane & 15);
        int col = tn * 256 + colt;
        size_t row = (size_t)(tm * 256 + rowt);
        size_t cidx = (size_t)head * c_hstride + row * c_rstride + col;
        float v = acc[i][j][r] + bptr[col];
        if (EPI == 1) {
          ((unsigned short*)Cv)[cidx] = f2bf(gelu_fast(v));
        } else if (EPI == 2) {
          v += resid[(size_t)head * r_hstride + row * r_rstride + col];
          ((float*)Cv)[cidx] = v;
        } else {
          ((float*)Cv)[cidx] = v;
        }
      }
    }
  }
}

extern "C" void kernel_launch(void* const* d_in, const int* in_sizes, int n_in,
                              void* d_out, int out_size, void* d_ws, size_t ws_size,
                              hipStream_t stream) {
  const float* x         = (const float*)d_in[0];
  const float* id_in     = (const float*)d_in[1];
  const float* in_proj_w = (const float*)d_in[2];
  const float* in_proj_b = (const float*)d_in[3];
  const float* norm_w    = (const float*)d_in[4];
  const float* up_w      = (const float*)d_in[5];
  const float* up_b      = (const float*)d_in[6];
  const float* down_w    = (const float*)d_in[7];
  const float* down_b    = (const float*)d_in[8];
  const float* q1_w      = (const float*)d_in[9];
  const float* q1_b      = (const float*)d_in[10];
  const float* q2_w      = (const float*)d_in[11];
  const float* q2_b      = (const float*)d_in[12];
  const float* k1_w      = (const float*)d_in[13];
  const float* k1_b      = (const float*)d_in[14];
  const float* k2_w      = (const float*)d_in[15];
  const float* k2_b      = (const float*)d_in[16];
  float* out = (float*)d_out;

  char* ws = (char*)d_ws;
  unsigned short* x_hm  = (unsigned short*)ws; ws += (size_t)BHROWS * DSTEER * 2;  // 109 MB (head-major)
  unsigned short* id_bf = (unsigned short*)ws; ws += (size_t)BHROWS * DID * 2;     // 8.4 MB
  float*          hbuf  = (float*)ws;          ws += (size_t)BHROWS * DS * 4;      // 67 MB (head-major)
  unsigned short* xn    = (unsigned short*)ws; ws += (size_t)BHROWS * DS * 2;      // 33.5 MB (head-major)
  unsigned short* hid   = (unsigned short*)ws; ws += (size_t)BHROWS * DHID * 2;    // 134 MB
  unsigned short* wbuf  = (unsigned short*)ws; ws += (size_t)HH * DHID * DS * 2;   // 67 MB (reused)

  // x -> bf16 head-major (single fused pass); id -> bf16 flat
  cvt_permute_kernel<<<BHROWS, 256, 0, stream>>>((const float4*)x, (uint4*)x_hm);
  cvt_bf16_kernel<<<512, 256, 0, stream>>>((const float4*)id_in, (uint2*)id_bf,
                                           (long)BHROWS * DID / 4);

  // ---- q path (HEAD-MAJOR: q1 A=x_hm, C=hid hm; q2 A=hid hm, C=out affine scatter) ----
  transpose_cvt_kernel<<<dim3(2 * HDQ / 64, DSTEER / 32, 1), 256, 0, stream>>>(
      q1_w, 0, wbuf, 0, DSTEER, 2 * HDQ);
  gemm256_kernel<1><<<1024, 512, 0, stream>>>(
      x_hm, (long long)1024 * DSTEER, DSTEER, wbuf, 0, q1_b, 0, nullptr, 0, 0,
      hid, (long long)1024 * 2 * HDQ, 2 * HDQ, 8, 32, DSTEER);
  transpose_cvt_kernel<<<dim3(HDQ / 64, 2 * HDQ / 32, 1), 256, 0, stream>>>(
      q2_w, 0, wbuf, 0, 2 * HDQ, HDQ);
  gemm256_kernel<0><<<512, 512, 0, stream>>>(
      hid, (long long)1024 * 2 * HDQ, 2 * HDQ, wbuf, 0, q2_b, 0, nullptr, 0, 0,
      out + 512, 2560, (long long)32 * 2560, 4, 16, 2 * HDQ);

  // ---- k path (flat rows) ----
  transpose_cvt_kernel<<<dim3(2 * HDQ / 64, DID / 32, 1), 256, 0, stream>>>(
      k1_w, 0, wbuf, 0, DID, 2 * HDQ);
  gemm256_kernel<1><<<1024, 512, 0, stream>>>(
      id_bf, 0, DID, wbuf, 0, k1_b, 0, nullptr, 0, 0,
      hid, 0, 2 * HDQ, 8, 1024, DID);
  transpose_cvt_kernel<<<dim3(HDQ / 64, 2 * HDQ / 32, 1), 256, 0, stream>>>(
      k2_w, 0, wbuf, 0, 2 * HDQ, HDQ);
  gemm256_kernel<0><<<512, 512, 0, stream>>>(
      hid, 0, 2 * HDQ, wbuf, 0, k2_b, 0, nullptr, 0, 0,
      out + 1536, 0, 2560, 4, 512, 2 * HDQ);

  // ---- content: in_proj (A = x_hm head-major; C -> hbuf head-major) ----
  transpose_cvt_kernel<<<dim3(DS / 64, DSTEER / 32, HH), 256, 0, stream>>>(
      in_proj_w, (long long)DSTEER * DS, wbuf, (long long)DS * DSTEER, DSTEER, DS);
  gemm256_kernel<0><<<256, 512, 0, stream>>>(
      x_hm, (long long)1024 * DSTEER, DSTEER, wbuf, (long long)DS * DSTEER,
      in_proj_b, DS, nullptr, 0, 0,
      hbuf, (long long)1024 * DS, DS, 2, 8, DSTEER);

  for (int i = 0; i < LL; i++) {
    rms_scale_kernel<<<8192, 256, 0, stream>>>(hbuf, norm_w, xn, i);
    transpose_cvt_kernel<<<dim3(DHID / 64, DS / 32, HH), 256, 0, stream>>>(
        up_w + (size_t)i * DS * DHID, (long long)LL * DS * DHID,
        wbuf, (long long)DHID * DS, DS, DHID);
    gemm256_kernel<1><<<1024, 512, 0, stream>>>(
        xn, (long long)1024 * DS, DS, wbuf, (long long)DHID * DS,
        up_b + (size_t)i * DHID, LL * DHID, nullptr, 0, 0,
        hid, (long long)1024 * DHID, DHID, 8, 32, DS);
    transpose_cvt_kernel<<<dim3(DS / 64, DHID / 32, HH), 256, 0, stream>>>(
        down_w + (size_t)i * DHID * DS, (long long)LL * DHID * DS,
        wbuf, (long long)DS * DHID, DHID, DS);
    if (i < 2) {
      gemm256_kernel<2><<<256, 512, 0, stream>>>(
          hid, (long long)1024 * DHID, DHID, wbuf, (long long)DS * DHID,
          down_b + (size_t)i * DS, LL * DS,
          hbuf, (long long)1024 * DS, DS,
          hbuf, (long long)1024 * DS, DS, 2, 8, DHID);
    } else {
      gemm256_kernel<2><<<256, 512, 0, stream>>>(
          hid, (long long)1024 * DHID, DHID, wbuf, (long long)DS * DHID,
          down_b + (size_t)i * DS, LL * DS,
          hbuf, (long long)1024 * DS, DS,
          out, 2560, (long long)32 * 2560, 2, 8, DHID);
    }
  }
}

// Round 20
// 1545.552 us; speedup vs baseline: 1.0935x; 1.0935x over previous
//
#include <hip/hip_runtime.h>
#include <hip/hip_bf16.h>
#include <math.h>

#define HH 32
#define LL 3
#define DS 512
#define DID 128
#define DSTEER 1664
#define DHID 2048
#define HDQ 1024
#define BHROWS 32768

typedef __attribute__((ext_vector_type(8))) short short8;
typedef __attribute__((ext_vector_type(4))) float f32x4;

typedef const __attribute__((address_space(1))) unsigned int* gptr_t;
typedef __attribute__((address_space(3))) unsigned int* lptr_t;

#define BAR() __builtin_amdgcn_s_barrier()
#define SB()  __builtin_amdgcn_sched_barrier(0)
#define VMCNT8() asm volatile("s_waitcnt vmcnt(8)")
#define VMCNT2() asm volatile("s_waitcnt vmcnt(2)")
#define VMCNT0() asm volatile("s_waitcnt vmcnt(0)")

__device__ __forceinline__ unsigned short f2bf(float f) {
  union { float f; unsigned int u; } x; x.f = f;
  unsigned int r = (x.u + 0x7FFFu + ((x.u >> 16) & 1u)) >> 16;
  return (unsigned short)r;
}
__device__ __forceinline__ unsigned int pk2(float a, float b) {
  return (unsigned int)f2bf(a) | ((unsigned int)f2bf(b) << 16);
}
// fast tanh-form gelu (validated r14/r15: absmax unchanged vs erff path)
__device__ __forceinline__ float gelu_fast(float v) {
  float u = 0.79788456080286536f * v * fmaf(0.044715f * v, v, 1.0f);
  u = fminf(fmaxf(u, -9.0f), 9.0f);
  float t = __builtin_amdgcn_exp2f(-2.8853900817779268f * u);
  float r = __builtin_amdgcn_rcpf(1.0f + t);
  float th = fmaf(-2.0f * t, r, 1.0f);
  return 0.5f * v * (1.0f + th);
}

// ---------- fp32 -> bf16 bulk convert ----------
__global__ void cvt_bf16_kernel(const float4* __restrict__ in, uint2* __restrict__ out, long n4) {
  long i = (long)blockIdx.x * blockDim.x + threadIdx.x;
  long stride = (long)gridDim.x * blockDim.x;
  for (; i < n4; i += stride) {
    float4 v = in[i];
    uint2 o; o.x = pk2(v.x, v.y); o.y = pk2(v.z, v.w);
    out[i] = o;
  }
}

// ---------- fused cvt + row-permute: fp32 rows (b*32+h) -> bf16 head-major (h*1024+b) ----------
__global__ void cvt_permute_kernel(const float4* __restrict__ in, uint4* __restrict__ out) {
  const int s = blockIdx.x;            // src row
  const int b = s >> 5, h = s & 31;
  const long d = (long)h * 1024 + b;   // dst row (head-major)
  const float4* src = in + (long)s * (DSTEER / 4);
  uint4* dst = out + d * (DSTEER / 8);
  int t = threadIdx.x;
  if (t < DSTEER / 8) {
    float4 a = src[2 * t], c = src[2 * t + 1];
    uint4 o;
    o.x = pk2(a.x, a.y); o.y = pk2(a.z, a.w);
    o.z = pk2(c.x, c.y); o.w = pk2(c.z, c.w);
    dst[t] = o;
  }
}

// ---------- batched transpose + convert: fp32 [R][C] -> bf16 [C][R] ----------
__global__ void transpose_cvt_kernel(const float* __restrict__ in, long long in_bstride,
                                     unsigned short* __restrict__ out, long long out_bstride,
                                     int R, int C) {
  __shared__ float t[64][33];
  const int r0 = blockIdx.y * 32;
  const int c0 = blockIdx.x * 64;
  const float* bin = in + (long long)blockIdx.z * in_bstride;
  unsigned short* bout = out + (long long)blockIdx.z * out_bstride;
  const int tid = threadIdx.x;
  const int col = tid & 63, rr = tid >> 6;
  #pragma unroll
  for (int j = 0; j < 8; j++) {
    int r = j * 4 + rr;
    t[col][r] = bin[(size_t)(r0 + r) * C + c0 + col];
  }
  __syncthreads();
  const int rq = (tid & 7) * 4;
  const int cc = tid >> 3;
  #pragma unroll
  for (int j = 0; j < 2; j++) {
    int c = j * 32 + cc;
    float v0 = t[c][rq], v1 = t[c][rq + 1], v2 = t[c][rq + 2], v3 = t[c][rq + 3];
    uint2 o; o.x = pk2(v0, v1); o.y = pk2(v2, v3);
    *(uint2*)&bout[(size_t)(c0 + c) * R + r0 + rq] = o;
  }
}

// ---------- RMS-norm + scale -> bf16 (HEAD-MAJOR rows) ----------
__global__ void rms_scale_kernel(const float* __restrict__ h,
                                 const float* __restrict__ norm_w,
                                 unsigned short* __restrict__ xn, int layer) {
  int gw = (int)((blockIdx.x * blockDim.x + threadIdx.x) >> 6);
  int lane = threadIdx.x & 63;
  if (gw >= BHROWS) return;
  int head = gw >> 10;
  const float4* hr = (const float4*)(h + (size_t)gw * DS);
  float4 v0 = hr[lane * 2], v1 = hr[lane * 2 + 1];
  float ss = v0.x*v0.x + v0.y*v0.y + v0.z*v0.z + v0.w*v0.w
           + v1.x*v1.x + v1.y*v1.y + v1.z*v1.z + v1.w*v1.w;
  #pragma unroll
  for (int off = 32; off > 0; off >>= 1) ss += __shfl_xor(ss, off, 64);
  float r = rsqrtf(ss * (1.0f / DS) + 1e-6f);
  const float4* nw = (const float4*)(norm_w + ((size_t)head * LL + layer) * DS);
  float4 w0 = nw[lane * 2], w1 = nw[lane * 2 + 1];
  uint4 o;
  o.x = pk2(v0.x * r * w0.x, v0.y * r * w0.y);
  o.y = pk2(v0.z * r * w0.z, v0.w * r * w0.w);
  o.z = pk2(v1.x * r * w1.x, v1.y * r * w1.y);
  o.w = pk2(v1.z * r * w1.z, v1.w * r * w1.w);
  *(uint4*)(xn + (size_t)gw * DS + (size_t)lane * 8) = o;
}

// ---------- 256x256 tile, BK=64, 8-wave, 4-phase pipelined bf16 GEMM ----------
// Best core across 20 rounds: 952 TF @ q1-class, 0 bank conflicts.
template<int EPI>
__global__ __launch_bounds__(512, 2)
void gemm256_kernel(const unsigned short* __restrict__ A, long long a_hstride, long long a_rstride,
                    const unsigned short* __restrict__ Bt, long long b_hstride,
                    const float* __restrict__ bias, int bias_hstride,
                    const float* __restrict__ resid, long long r_hstride, long long r_rstride,
                    void* __restrict__ Cv, long long c_hstride, long long c_rstride,
                    int gx, int tph, int K) {
  __shared__ unsigned short lds[2 * 2 * 256 * 64];  // 128 KiB
  const int tid = threadIdx.x;
  const int lane = tid & 63;
  const int wave = tid >> 6;
  const int wr = wave >> 2, wc = wave & 3;
  const int ntot = gridDim.x;
  int id = blockIdx.x;
  { int cpx = ntot >> 3; id = (id & 7) * cpx + (id >> 3); }  // bijective: ntot%8==0
  const int head = id / tph;
  const int rem = id % tph;
  const int tn = rem % gx, tm = rem / gx;

  // ---- staging addressing (per-lane source, linear LDS dest) ----
  const int l3 = lane >> 3;
  const int gslot = ((lane & 7) ^ l3) * 8;
  const int mbase = wave * 8 + l3;
  const int nbase = (wave >> 2) * 64 + (wave & 3) * 8 + l3;
  const unsigned short* pA = A + (size_t)head * a_hstride
                               + (size_t)(tm * 256 + mbase) * a_rstride + gslot;
  const unsigned short* pB = Bt + (size_t)head * b_hstride
                               + (size_t)(tn * 256 + nbase) * K + gslot;
  const size_t aBlk = (size_t)64 * a_rstride;

  // ---- fragment read addressing (16x16x32 maps; r7-verified) ----
  const int physk0 = ((lane >> 4) ^ (lane & 7)) * 8;
  const int physk1 = ((4 + (lane >> 4)) ^ (lane & 7)) * 8;
  const int aRow = wr * 128 + (lane & 15);
  const int bRow = wc * 32 + (lane & 15);

  auto stageA = [&](unsigned short* dstA, int h, size_t kels) {
    #pragma unroll
    for (int i = 0; i < 2; ++i)
      __builtin_amdgcn_global_load_lds(
          (gptr_t)(pA + (size_t)(i * 2 + h) * aBlk + kels),
          (lptr_t)(dstA + ((i * 2 + h) * 64 + wave * 8) * 64), 16, 0, 0);
  };
  auto stageB = [&](unsigned short* dstB, int h, size_t kels) {
    #pragma unroll
    for (int i = 0; i < 2; ++i)
      __builtin_amdgcn_global_load_lds(
          (gptr_t)(pB + (size_t)(i * 128 + h * 32) * K + kels),
          (lptr_t)(dstB + (h * 128 + i * 64 + wave * 8) * 64), 16, 0, 0);
  };

  f32x4 acc[8][4];
  #pragma unroll
  for (int i = 0; i < 8; ++i)
    #pragma unroll
    for (int j = 0; j < 4; ++j) acc[i][j] = (f32x4){0.f, 0.f, 0.f, 0.f};
  short8 a[4][2], b[4][2];

  const int T = K >> 6;
  // ---- prologue: tile0 {A0,B0,B1,A1} + tile1 {A0,B0,B1} ----
  stageA(lds, 0, 0);
  stageB(lds + 16384, 0, 0);
  stageB(lds + 16384, 1, 0);
  stageA(lds, 1, 0);
  stageA(lds + 32768, 0, 64);
  stageB(lds + 32768 + 16384, 0, 64);
  stageB(lds + 32768 + 16384, 1, 64);
  VMCNT8();
  SB();
  BAR();

  for (int t = 0; t < T; ++t) {
    unsigned short* rA = lds + (t & 1) * 32768;
    unsigned short* rB = rA + 16384;
    unsigned short* nA = lds + ((t + 1) & 1) * 32768;
    const size_t k1 = (size_t)(t + 1) * 64;
    const size_t k2 = (size_t)(t + 2) * 64;
    const bool m1 = (t + 1 < T), m2 = (t + 2 < T);

    // ======== P0: read b01 + a-lo; stage A-hi(t+1); MFMA Q00 ========
    #pragma unroll
    for (int j = 0; j < 2; ++j) {
      b[j][0] = *(const short8*)&rB[(bRow + j * 16) * 64 + physk0];
      b[j][1] = *(const short8*)&rB[(bRow + j * 16) * 64 + physk1];
    }
    #pragma unroll
    for (int i = 0; i < 4; ++i) {
      a[i][0] = *(const short8*)&rA[(aRow + i * 16) * 64 + physk0];
      a[i][1] = *(const short8*)&rA[(aRow + i * 16) * 64 + physk1];
    }
    if (m1) stageA(nA, 1, k1);
    __builtin_amdgcn_s_setprio(1);
    #pragma unroll
    for (int i = 0; i < 4; ++i)
      #pragma unroll
      for (int j = 0; j < 2; ++j) {
        acc[i][j] = __builtin_amdgcn_mfma_f32_16x16x32_bf16(a[i][0], b[j][0], acc[i][j], 0, 0, 0);
        acc[i][j] = __builtin_amdgcn_mfma_f32_16x16x32_bf16(a[i][1], b[j][1], acc[i][j], 0, 0, 0);
      }
    __builtin_amdgcn_s_setprio(0);
    BAR();

    // ======== P1: read b23; MFMA Q01; wait A-hi(t) ========
    #pragma unroll
    for (int j = 0; j < 2; ++j) {
      b[2 + j][0] = *(const short8*)&rB[(128 + bRow + j * 16) * 64 + physk0];
      b[2 + j][1] = *(const short8*)&rB[(128 + bRow + j * 16) * 64 + physk1];
    }
    __builtin_amdgcn_s_setprio(1);
    #pragma unroll
    for (int i = 0; i < 4; ++i)
      #pragma unroll
      for (int j = 0; j < 2; ++j) {
        acc[i][2 + j] = __builtin_amdgcn_mfma_f32_16x16x32_bf16(a[i][0], b[2 + j][0], acc[i][2 + j], 0, 0, 0);
        acc[i][2 + j] = __builtin_amdgcn_mfma_f32_16x16x32_bf16(a[i][1], b[2 + j][1], acc[i][2 + j], 0, 0, 0);
      }
    __builtin_amdgcn_s_setprio(0);
    if (m1) { VMCNT8(); } else { VMCNT0(); }
    SB();
    BAR();

    // ======== P2: read a-hi; stage A-lo(t+2)+B-lo(t+2); MFMA Q11 ========
    #pragma unroll
    for (int i = 0; i < 4; ++i) {
      a[i][0] = *(const short8*)&rA[(aRow + (4 + i) * 16) * 64 + physk0];
      a[i][1] = *(const short8*)&rA[(aRow + (4 + i) * 16) * 64 + physk1];
    }
    if (m2) { stageA(rA, 0, k2); stageB(rB, 0, k2); }
    __builtin_amdgcn_s_setprio(1);
    #pragma unroll
    for (int i = 0; i < 4; ++i)
      #pragma unroll
      for (int j = 0; j < 2; ++j) {
        acc[4 + i][2 + j] = __builtin_amdgcn_mfma_f32_16x16x32_bf16(a[i][0], b[2 + j][0], acc[4 + i][2 + j], 0, 0, 0);
        acc[4 + i][2 + j] = __builtin_amdgcn_mfma_f32_16x16x32_bf16(a[i][1], b[2 + j][1], acc[4 + i][2 + j], 0, 0, 0);
      }
    __builtin_amdgcn_s_setprio(0);
    BAR();

    // ======== P3: stage B-hi(t+2); MFMA Q10; wait tile(t+1) ========
    if (m2) stageB(rB, 1, k2);
    __builtin_amdgcn_s_setprio(1);
    #pragma unroll
    for (int i = 0; i < 4; ++i)
      #pragma unroll
      for (int j = 0; j < 2; ++j) {
        acc[4 + i][j] = __builtin_amdgcn_mfma_f32_16x16x32_bf16(a[i][0], b[j][0], acc[4 + i][j], 0, 0, 0);
        acc[4 + i][j] = __builtin_amdgcn_mfma_f32_16x16x32_bf16(a[i][1], b[j][1], acc[4 + i][j], 0, 0, 0);
      }
    __builtin_amdgcn_s_setprio(0);
    if (m2) { VMCNT8(); } else if (m1) { VMCNT2(); }
    SB();
    BAR();
  }

  // ---- epilogue ----
  const float* bptr = bias + (size_t)head * bias_hstride;
  #pragma unroll
  for (int i = 0; i < 8; ++i) {
    #pragma unroll
    for (int j = 0; j < 4; ++j) {
      #pragma unroll
      for (int r = 0; r < 4; ++r) {
        int rowt = wr * 128 + i * 16 + (lane >> 4) * 4 + r;
        int colt = wc * 64 + j * 16 + (lane & 15);
        int col = tn * 256 + colt;
        size_t row = (size_t)(tm * 256 + rowt);
        size_t cidx = (size_t)head * c_hstride + row * c_rstride + col;
        float v = acc[i][j][r] + bptr[col];
        if (EPI == 1) {
          ((unsigned short*)Cv)[cidx] = f2bf(gelu_fast(v));
        } else if (EPI == 2) {
          v += resid[(size_t)head * r_hstride + row * r_rstride + col];
          ((float*)Cv)[cidx] = v;
        } else {
          ((float*)Cv)[cidx] = v;
        }
      }
    }
  }
}

extern "C" void kernel_launch(void* const* d_in, const int* in_sizes, int n_in,
                              void* d_out, int out_size, void* d_ws, size_t ws_size,
                              hipStream_t stream) {
  const float* x         = (const float*)d_in[0];
  const float* id_in     = (const float*)d_in[1];
  const float* in_proj_w = (const float*)d_in[2];
  const float* in_proj_b = (const float*)d_in[3];
  const float* norm_w    = (const float*)d_in[4];
  const float* up_w      = (const float*)d_in[5];
  const float* up_b      = (const float*)d_in[6];
  const float* down_w    = (const float*)d_in[7];
  const float* down_b    = (const float*)d_in[8];
  const float* q1_w      = (const float*)d_in[9];
  const float* q1_b      = (const float*)d_in[10];
  const float* q2_w      = (const float*)d_in[11];
  const float* q2_b      = (const float*)d_in[12];
  const float* k1_w      = (const float*)d_in[13];
  const float* k1_b      = (const float*)d_in[14];
  const float* k2_w      = (const float*)d_in[15];
  const float* k2_b      = (const float*)d_in[16];
  float* out = (float*)d_out;

  char* ws = (char*)d_ws;
  unsigned short* x_hm  = (unsigned short*)ws; ws += (size_t)BHROWS * DSTEER * 2;  // 109 MB (head-major)
  unsigned short* id_bf = (unsigned short*)ws; ws += (size_t)BHROWS * DID * 2;     // 8.4 MB
  float*          hbuf  = (float*)ws;          ws += (size_t)BHROWS * DS * 4;      // 67 MB (head-major)
  unsigned short* xn    = (unsigned short*)ws; ws += (size_t)BHROWS * DS * 2;      // 33.5 MB (head-major)
  unsigned short* hid   = (unsigned short*)ws; ws += (size_t)BHROWS * DHID * 2;    // 134 MB
  unsigned short* wbuf  = (unsigned short*)ws; ws += (size_t)HH * DHID * DS * 2;   // 67 MB (reused)

  // x -> bf16 head-major (single fused pass); id -> bf16 flat
  cvt_permute_kernel<<<BHROWS, 256, 0, stream>>>((const float4*)x, (uint4*)x_hm);
  cvt_bf16_kernel<<<512, 256, 0, stream>>>((const float4*)id_in, (uint2*)id_bf,
                                           (long)BHROWS * DID / 4);

  // ---- q path (HEAD-MAJOR: q1 A=x_hm, C=hid hm; q2 A=hid hm, C=out affine scatter) ----
  transpose_cvt_kernel<<<dim3(2 * HDQ / 64, DSTEER / 32, 1), 256, 0, stream>>>(
      q1_w, 0, wbuf, 0, DSTEER, 2 * HDQ);
  gemm256_kernel<1><<<1024, 512, 0, stream>>>(
      x_hm, (long long)1024 * DSTEER, DSTEER, wbuf, 0, q1_b, 0, nullptr, 0, 0,
      hid, (long long)1024 * 2 * HDQ, 2 * HDQ, 8, 32, DSTEER);
  transpose_cvt_kernel<<<dim3(HDQ / 64, 2 * HDQ / 32, 1), 256, 0, stream>>>(
      q2_w, 0, wbuf, 0, 2 * HDQ, HDQ);
  gemm256_kernel<0><<<512, 512, 0, stream>>>(
      hid, (long long)1024 * 2 * HDQ, 2 * HDQ, wbuf, 0, q2_b, 0, nullptr, 0, 0,
      out + 512, 2560, (long long)32 * 2560, 4, 16, 2 * HDQ);

  // ---- k path (flat rows) ----
  transpose_cvt_kernel<<<dim3(2 * HDQ / 64, DID / 32, 1), 256, 0, stream>>>(
      k1_w, 0, wbuf, 0, DID, 2 * HDQ);
  gemm256_kernel<1><<<1024, 512, 0, stream>>>(
      id_bf, 0, DID, wbuf, 0, k1_b, 0, nullptr, 0, 0,
      hid, 0, 2 * HDQ, 8, 1024, DID);
  transpose_cvt_kernel<<<dim3(HDQ / 64, 2 * HDQ / 32, 1), 256, 0, stream>>>(
      k2_w, 0, wbuf, 0, 2 * HDQ, HDQ);
  gemm256_kernel<0><<<512, 512, 0, stream>>>(
      hid, 0, 2 * HDQ, wbuf, 0, k2_b, 0, nullptr, 0, 0,
      out + 1536, 0, 2560, 4, 512, 2 * HDQ);

  // ---- content: in_proj (A = x_hm head-major; C -> hbuf head-major) ----
  transpose_cvt_kernel<<<dim3(DS / 64, DSTEER / 32, HH), 256, 0, stream>>>(
      in_proj_w, (long long)DSTEER * DS, wbuf, (long long)DS * DSTEER, DSTEER, DS);
  gemm256_kernel<0><<<256, 512, 0, stream>>>(
      x_hm, (long long)1024 * DSTEER, DSTEER, wbuf, (long long)DS * DSTEER,
      in_proj_b, DS, nullptr, 0, 0,
      hbuf, (long long)1024 * DS, DS, 2, 8, DSTEER);

  for (int i = 0; i < LL; i++) {
    rms_scale_kernel<<<8192, 256, 0, stream>>>(hbuf, norm_w, xn, i);
    transpose_cvt_kernel<<<dim3(DHID / 64, DS / 32, HH), 256, 0, stream>>>(
        up_w + (size_t)i * DS * DHID, (long long)LL * DS * DHID,
        wbuf, (long long)DHID * DS, DS, DHID);
    gemm256_kernel<1><<<1024, 512, 0, stream>>>(
        xn, (long long)1024 * DS, DS, wbuf, (long long)DHID * DS,
        up_b + (size_t)i * DHID, LL * DHID, nullptr, 0, 0,
        hid, (long long)1024 * DHID, DHID, 8, 32, DS);
    transpose_cvt_kernel<<<dim3(DS / 64, DHID / 32, HH), 256, 0, stream>>>(
        down_w + (size_t)i * DHID * DS, (long long)LL * DHID * DS,
        wbuf, (long long)DS * DHID, DHID, DS);
    if (i < 2) {
      gemm256_kernel<2><<<256, 512, 0, stream>>>(
          hid, (long long)1024 * DHID, DHID, wbuf, (long long)DS * DHID,
          down_b + (size_t)i * DS, LL * DS,
          hbuf, (long long)1024 * DS, DS,
          hbuf, (long long)1024 * DS, DS, 2, 8, DHID);
    } else {
      gemm256_kernel<2><<<256, 512, 0, stream>>>(
          hid, (long long)1024 * DHID, DHID, wbuf, (long long)DS * DHID,
          down_b + (size_t)i * DS, LL * DS,
          hbuf, (long long)1024 * DS, DS,
          out, 2560, (long long)32 * 2560, 2, 8, DHID);
    }
  }
}